// Round 13
// baseline (132.565 us; speedup 1.0000x reference)
//
#include <hip/hip_runtime.h>
#include <hip/hip_fp16.h>

// 21-qubit batched (B=4) state-vector simulator, 6 split passes + k_red.
// R13: occupancy 2x with identical issue work. fp16 LDS tiles (32KB) =>
// TWO tiles per 1024-thread block (half = tid>>9, per-half 32KB LDS, per-half
// virtual bid = blockIdx.x*2+half). Grid 256 -> 2 blocks/CU x 16 waves =
// 32 waves/CU = 8 waves/SIMD (was 4). __launch_bounds__(1024,8) pins VGPR<=64
// (R6 evidence: this body fits 64). Sweep algebra byte-identical to R11.
// fp16 global state, XCD batch affinity. Qubit q <-> g-bit (20-q).

#define NQ 21
#define SHC(q) __shfl(cv, (q)), __shfl(sv, (q))

__device__ __forceinline__ int PH2B(int blk) {        // granule swizzle
  return blk ^ ((blk >> 3) & 7) ^ ((blk >> 6) & 7);
}

template<int Q>
__device__ __forceinline__ void ry32(float* v, float c, float s) {
#pragma unroll
  for (int k = 0; k < 16; ++k) {
    int l0 = ((k >> Q) << (Q + 1)) | (k & ((1 << Q) - 1));
    int l1 = l0 | (1 << Q);
    float a0 = v[l0], a1 = v[l1];
    v[l0] = c * a0 - s * a1;
    v[l1] = s * a0 + c * a1;
  }
}

template<int C, int T>
__device__ __forceinline__ void cnot32(float* v) {
  constexpr int lo = (C < T) ? C : T;
  constexpr int hi = (C < T) ? T : C;
#pragma unroll
  for (int k = 0; k < 8; ++k) {
    int i1 = ((k >> lo) << (lo + 1)) | (k & ((1 << lo) - 1));
    int i2 = ((i1 >> hi) << (hi + 1)) | (i1 & ((1 << hi) - 1));
    int a = i2 | (1 << C);
    int b = a | (1 << T);
    float tmp = v[a]; v[a] = v[b]; v[b] = tmp;
  }
}

// fp16 helpers: 4 amps (8B) <-> 4 f32 regs ; 2 amps <-> 1 uint
__device__ __forceinline__ void uh4(uint2 u, float* d) {
  __half2 h0 = *reinterpret_cast<__half2*>(&u.x);
  __half2 h1 = *reinterpret_cast<__half2*>(&u.y);
  float2 f0 = __half22float2(h0), f1 = __half22float2(h1);
  d[0] = f0.x; d[1] = f0.y; d[2] = f1.x; d[3] = f1.y;
}
__device__ __forceinline__ void ld4(const uint2* __restrict__ g, int idx, float* dst) {
  uh4(g[idx], dst);
}
__device__ __forceinline__ unsigned pkh(float a, float b) {
  __half2 h = __floats2half2_rn(a, b);
  return *reinterpret_cast<unsigned*>(&h);
}

#define A1 (tid | (rr << 9))
#define GH(l4) (((l4) & 0xF) | (t << 4) | (((l4) >> 4) << 11))

// per-half virtual block decode (two tiles per 1024-thread block)
#define HALF_DECODE                                                            \
  const int tid = threadIdx.x & 511, lane = threadIdx.x & 63;                  \
  const int half = threadIdx.x >> 9;                                           \
  const int bidv = (blockIdx.x << 1) | half;                                   \
  const int b = (bidv & 7) >> 1;                                               \
  const int t = ((bidv >> 3) << 1) | (bidv & 1);

// sigma2-style write (S1/HS1): pairs over v-bit2 (b32 writes)
#define WR_SIGMA2(hs, v)                                                       \
  {                                                                            \
    const int pbs = (((tid >> 5) & 1) << 1) | ((tid & 31) << 2) |              \
                    (((tid >> 6) & 7) << 9);                                   \
    _Pragma("unroll") for (int i = 0; i < 16; ++i) {                           \
      int r = (i & 3) | ((i >> 2) << 3);                                       \
      int sl = pbs ^ (((i & 3) << 7) | ((i >> 2) << 12));                      \
      int a = (PH2B(sl >> 2) << 2) | (sl & 3);                                 \
      (hs)[a >> 1] = pkh((v)[r], (v)[r | 4]);                                  \
    }                                                                          \
  }

// sigma2-style read (S2/HS2): granule (4 amps) = uint2 b64 read + unpack
#define RD_SIGMA2(hs2, v)                                                      \
  {                                                                            \
    const int pbb = (tid & 31) | (((tid >> 5) & 3) << 5) |                     \
                    (((tid >> 7) & 3) << 10);                                  \
    _Pragma("unroll") for (int rr = 0; rr < 8; ++rr)                           \
      uh4((hs2)[PH2B(pbb ^ (rr << 7))], (v) + 4 * rr);                         \
  }

// ---------------- L pass: tile = bits 0..13, t = bits 14..20 ----------------
template<bool INIT>
__global__ __launch_bounds__(1024, 8) void k_L(const float* __restrict__ x,
                                               const float* __restrict__ w,
                                               unsigned long long stp) {
  __shared__ __align__(16) unsigned hs_all[16384];    // 2 halves x 32 KB
  HALF_DECODE;
  unsigned* hs = hs_all + (half << 13);
  uint2* hs2 = reinterpret_cast<uint2*>(hs);
  float cv = 1.f, sv = 0.f;
  if (lane < NQ) sincosf(0.5f * w[lane], &sv, &cv);
  uint2* g2 = reinterpret_cast<uint2*>(stp) + ((size_t)b << 19) + ((size_t)t << 12);
  float v[32];

  // ---- S1: v = {amp0,amp1 | rr=amp11,12,13}: C(13,12),(12,11); RY q7,q8 ----
  if (INIT) {
    float cx = 1.f, sx = 0.f;
    if (lane < NQ) sincosf(0.5f * x[b * NQ + lane], &sx, &cx);
    float Qp = 1.f;
#pragma unroll
    for (int i = 0; i < 9; ++i) {            // tid bit i -> g(2+i) -> qubit 18-i
      float cq = __shfl(cx, 18 - i), sq = __shfl(sx, 18 - i);
      Qp *= ((tid >> i) & 1) ? sq : cq;
    }
    float hfac[2];
#pragma unroll
    for (int bb = 0; bb < 2; ++bb) {         // g13 = bb, h = g[13..20]
      int h = (t << 1) | bb;
      int h0 = h ^ (h >> 1);                 // pre-image of high chain
      float p = 1.f;
#pragma unroll
      for (int j = 0; j < 8; ++j) {
        float cq = __shfl(cx, 7 - j), sq = __shfl(sx, 7 - j);
        p *= ((h0 >> j) & 1) ? sq : cq;
      }
      hfac[bb] = p;
    }
    float c20 = __shfl(cx, 20), s20 = __shfl(sx, 20);
    float c19 = __shfl(cx, 19), s19 = __shfl(sx, 19);
    float c9  = __shfl(cx, 9),  s9  = __shfl(sx, 9);
    float c8  = __shfl(cx, 8),  s8  = __shfl(sx, 8);
    float w0t[4], w1t[4];
#pragma unroll
    for (int i = 0; i < 4; ++i) {
      w0t[i] = ((i & 1) ? s20 : c20) * ((i & 2) ? s19 : c19);  // amps 0,1
      w1t[i] = ((i & 1) ? s9  : c9 ) * ((i & 2) ? s8  : c8 );  // amps 11,12
    }
#pragma unroll
    for (int r = 0; r < 32; ++r)
      v[r] = hfac[(r >> 4) & 1] * w1t[(r >> 2) & 3] * w0t[r & 3] * Qp;
  } else {
#pragma unroll
    for (int rr = 0; rr < 8; ++rr) ld4(g2, A1, v + 4 * rr);
  }
  cnot32<4, 3>(v); cnot32<3, 2>(v);
  ry32<4>(v, SHC(7)); ry32<3>(v, SHC(8));
  WR_SIGMA2(hs, v);                          // s0=amp11
  __syncthreads();

  // ---- S2: v = {amp11,amp7 | rr=amp8,9,10}: C(11,10),(10,9),(9,8),(8,7) ----
  RD_SIGMA2(hs2, v);
  cnot32<0, 4>(v); cnot32<4, 3>(v); cnot32<3, 2>(v); cnot32<2, 1>(v);
  ry32<0>(v, SHC(9)); ry32<4>(v, SHC(10)); ry32<3>(v, SHC(11)); ry32<2>(v, SHC(12));
  __syncthreads();
  {
    // sigma3: s0=amp7(pair), s1=amp3, s2=amp4, s3=amp5, s4=amp6, s5=amp2,
    // s6=amp1, s7=amp0, s8..10=amp8..10, s11=amp11, s12,13=amp12,13
    const int pbs = (tid & 0x1E) | ((tid & 1) << 5) | (tid & 0x40) |
                    (((tid >> 5) & 1) << 7) | ((tid >> 7) << 12);
#pragma unroll
    for (int i = 0; i < 16; ++i) {
      int r = (i & 1) | ((i >> 1) << 2);
      int sl = pbs ^ ((((i >> 1) & 7) << 8) | ((i & 1) << 11));
      int a = (PH2B(sl >> 2) << 2) | (sl & 3);
      hs[a >> 1] = pkh(v[r], v[r | 2]);
    }
  }
  __syncthreads();

  // ---- S3: v = {amp7,amp3 | rr=amp4,5,6}: C(7,6),(6,5),(5,4),(4,3) ----
  {
    const int pbb = ((tid & 7) << 3) | (((tid >> 3) & 7) << 6) | (((tid >> 6) & 7) << 9);
#pragma unroll
    for (int rr = 0; rr < 8; ++rr) uh4(hs2[PH2B(pbb | rr)], v + 4 * rr);
  }
  cnot32<0, 4>(v); cnot32<4, 3>(v); cnot32<3, 2>(v); cnot32<2, 1>(v);
  ry32<0>(v, SHC(13)); ry32<4>(v, SHC(14)); ry32<3>(v, SHC(15)); ry32<2>(v, SHC(16));
  __syncthreads();
  {
    // identity'': s0=amp3, s1=amp4 (quads), s2=amp0, s3=amp1, s4=amp2,
    // s5=amp5, s6=amp6, s7=amp7, s8..13=amp8..13  (b64 quad writes)
    const int pbs = (((tid >> 2) & 1) << 2) | (((tid >> 1) & 1) << 3) |
                    ((tid & 1) << 4) | (((tid >> 3) & 7) << 8) |
                    (((tid >> 6) & 7) << 11);
#pragma unroll
    for (int i = 0; i < 8; ++i) {
      int r = (i & 1) | ((i >> 1) << 3);
      int sl = pbs ^ ((((i >> 1) & 1) << 5) | (((i >> 2) & 1) << 6) | ((i & 1) << 7));
      uint2 o; o.x = pkh(v[r], v[r | 2]); o.y = pkh(v[r | 4], v[r | 6]);
      hs2[PH2B(sl >> 2)] = o;
    }
  }
  __syncthreads();

  // ---- S4: v = {amp3,amp4 | rr=amp0,1,2}: C(3,2),(2,1),(1,0); RY q17..q19 ----
  {
    const int pbb = tid << 3;
#pragma unroll
    for (int rr = 0; rr < 8; ++rr) uh4(hs2[PH2B(pbb | rr)], v + 4 * rr);
  }
  cnot32<0, 4>(v); cnot32<4, 3>(v); cnot32<3, 2>(v);
  ry32<0>(v, SHC(17)); ry32<4>(v, SHC(18)); ry32<3>(v, SHC(19));
  {
    uint4* g4o = reinterpret_cast<uint4*>(g2);
#pragma unroll
    for (int i = 0; i < 4; ++i) {            // i = {a3, a4}
      int c = (i & 1) | ((i >> 1) << 1);
      uint4 o;
      o.x = pkh(v[c], v[c + 4]);   o.y = pkh(v[c + 8], v[c + 12]);
      o.z = pkh(v[c + 16], v[c + 20]); o.w = pkh(v[c + 24], v[c + 28]);
      g4o[(i & 1) | ((i >> 1) << 1) | (tid << 2)] = o;
    }
  }
}

// ---------------- H pass: tile = {g0..g5, g13..g20} (l0..l5, l6..l13) ----------------
__global__ __launch_bounds__(1024, 8) void k_H(const float* __restrict__ w,
                                               unsigned long long stp) {
  __shared__ __align__(16) unsigned hs_all[16384];
  HALF_DECODE;
  unsigned* hs = hs_all + (half << 13);
  uint2* hs2 = reinterpret_cast<uint2*>(hs);
  float cv = 1.f, sv = 0.f;
  if (lane < NQ) sincosf(0.5f * w[lane], &sv, &cv);
  uint2* gb = reinterpret_cast<uint2*>(stp) + ((size_t)b << 19);
  float v[32];

  // ---- HS1: v = {l0,l1 | rr=l11,l12,l13}: wrap C(g0,g20); RY q20,q0,q1,q2;
  //      next-layer chain C(l13,l12),(l12,l11) ----
#pragma unroll
  for (int rr = 0; rr < 8; ++rr) ld4(gb, GH(A1), v + 4 * rr);
  cnot32<0, 4>(v);
  ry32<0>(v, SHC(20)); ry32<4>(v, SHC(0)); ry32<3>(v, SHC(1)); ry32<2>(v, SHC(2));
  cnot32<4, 3>(v); cnot32<3, 2>(v);
  WR_SIGMA2(hs, v);                          // s0=l11
  __syncthreads();

  // ---- HS2: v = {l11,l7 | rr=l8,l9,l10}: RY q3..q6; chain C(l11,l10)..(l8,l7) ----
  RD_SIGMA2(hs2, v);
  ry32<4>(v, SHC(3)); ry32<3>(v, SHC(4)); ry32<2>(v, SHC(5)); ry32<1>(v, SHC(6));
  cnot32<0, 4>(v); cnot32<4, 3>(v); cnot32<3, 2>(v); cnot32<2, 1>(v);
  __syncthreads();
  {
    // sigma3H: s0=l7(pair), s1=l5, s2=l0, s3=l1, s4=l6, s5=l2, s6=l3, s7=l4,
    // s8..10=l8..10, s11=l11, s12,13=l12,13
    const int pbs = (((tid >> 3) & 1) << 1) | (((tid >> 5) & 1) << 2) |
                    (((tid >> 6) & 1) << 3) | (tid & 16) | ((tid & 1) << 5) |
                    (((tid >> 1) & 1) << 6) | (((tid >> 2) & 1) << 7) |
                    ((tid >> 7) << 12);
#pragma unroll
    for (int i = 0; i < 16; ++i) {
      int r = (i & 1) | ((i >> 1) << 2);
      int sl = pbs ^ ((((i >> 1) & 7) << 8) | ((i & 1) << 11));
      int a = (PH2B(sl >> 2) << 2) | (sl & 3);
      hs[a >> 1] = pkh(v[r], v[r | 2]);
    }
  }
  __syncthreads();

  // ---- HS3: v = {l7,l5 | rr=l0,l1,l6}: chain C(l7,l6); store ----
  {
    const int pbb = ((tid & 7) << 3) | (((tid >> 3) & 7) << 6) | (((tid >> 6) & 7) << 9);
#pragma unroll
    for (int rr = 0; rr < 8; ++rr) uh4(hs2[PH2B(pbb | rr)], v + 4 * rr);
  }
  cnot32<0, 4>(v);
#pragma unroll
  for (int i = 0; i < 8; ++i) {              // i = {r0(l7), r1(l5), r4(l6)}
    int r0 = i & 1, r1 = (i >> 1) & 1, rh = (i >> 2) & 1;
    int c = r0 | (r1 << 1) | (rh << 4);
    int gidx = (tid & 7) | (r1 << 3) | (t << 4) |
               ((rh | (r0 << 1) | (((tid >> 3) & 0x3F) << 2)) << 11);
    uint2 o; o.x = pkh(v[c], v[c + 4]); o.y = pkh(v[c + 8], v[c + 12]);
    gb[gidx] = o;
  }
}

// ---------------- final H pass + measurement ----------------
__global__ __launch_bounds__(1024, 8) void k_Hfin(const float* __restrict__ w,
                                                  unsigned long long stp,
                                                  float* __restrict__ partial) {
  __shared__ __align__(16) unsigned hs_all[16384];
  HALF_DECODE;
  unsigned* hs = hs_all + (half << 13);
  uint2* hs2 = reinterpret_cast<uint2*>(hs);
  float* red = reinterpret_cast<float*>(hs);          // per-half, reused post-reads
  float cv = 1.f, sv = 0.f;
  if (lane < NQ) sincosf(0.5f * w[lane], &sv, &cv);
  const uint2* gb = reinterpret_cast<const uint2*>(stp) + ((size_t)b << 19);
  float v[32];

  // ---- HS1f: wrap; RY q20,q0,q1,q2 ----
#pragma unroll
  for (int rr = 0; rr < 8; ++rr) ld4(gb, GH(A1), v + 4 * rr);
  cnot32<0, 4>(v);
  ry32<0>(v, SHC(20)); ry32<4>(v, SHC(0)); ry32<3>(v, SHC(1)); ry32<2>(v, SHC(2));
  WR_SIGMA2(hs, v);
  __syncthreads();

  // ---- HS2f: v = {l11,l7 | rr=l8,l9,l10}: RY q3..q6; measure ----
  RD_SIGMA2(hs2, v);
  __syncthreads();   // all LDS reads done; hs reused for reduction below
  ry32<4>(v, SHC(3)); ry32<3>(v, SHC(4)); ry32<2>(v, SHC(5)); ry32<1>(v, SHC(6));

  // v bits: 0=l11(q2), 1=l7(q6), 2=l8(q5), 3=l9(q4), 4=l10(q3)
  float S = 0, aq2 = 0, aq6 = 0, aq5 = 0, aq4 = 0, aq3 = 0;
#pragma unroll
  for (int r = 0; r < 32; ++r) {
    float p = v[r] * v[r];
    S += p;
    aq2 += (r & 1)  ? -p : p;
    aq6 += (r & 2)  ? -p : p;
    aq5 += (r & 4)  ? -p : p;
    aq4 += (r & 8)  ? -p : p;
    aq3 += (r & 16) ? -p : p;
  }
  float a21[21];
  a21[2] = aq2; a21[6] = aq6; a21[5] = aq5; a21[4] = aq4; a21[3] = aq3;
  a21[18] = (tid & 1)   ? -S : S;
  a21[17] = (tid & 2)   ? -S : S;
  a21[16] = (tid & 4)   ? -S : S;
  a21[15] = (tid & 8)   ? -S : S;
  a21[7]  = (tid & 16)  ? -S : S;
  a21[20] = (tid & 32)  ? -S : S;
  a21[19] = (tid & 64)  ? -S : S;
  a21[1]  = (tid & 128) ? -S : S;
  a21[0]  = (tid & 256) ? -S : S;
  a21[14] = (t & 1)  ? -S : S;     // t bits = g6..g12 -> q14..q8
  a21[13] = (t & 2)  ? -S : S;
  a21[12] = (t & 4)  ? -S : S;
  a21[11] = (t & 8)  ? -S : S;
  a21[10] = (t & 16) ? -S : S;
  a21[9]  = (t & 32) ? -S : S;
  a21[8]  = (t & 64) ? -S : S;

  const int wv = tid >> 6;
#pragma unroll
  for (int q = 0; q < 21; ++q) {
    float val = a21[q];
    val += __shfl_down(val, 32);
    val += __shfl_down(val, 16);
    val += __shfl_down(val, 8);
    val += __shfl_down(val, 4);
    val += __shfl_down(val, 2);
    val += __shfl_down(val, 1);
    if (lane == 0) red[q * 8 + wv] = val;
  }
  __syncthreads();
  if (tid < NQ) {
    float sum = 0.f;
#pragma unroll
    for (int k = 0; k < 8; ++k) sum += red[tid * 8 + k];
    partial[((b << 7) | t) * NQ + tid] = sum;
  }
}

// ---------------- deterministic final reduction (1 block x 672) ----------------
__global__ void k_red(const float* __restrict__ partial, float* __restrict__ out) {
  __shared__ float red[84][8];
  const int tid = threadIdx.x;
  const int pair = tid >> 3, k8 = tid & 7;
  if (pair < 84) {
    int b = pair / NQ, q = pair % NQ;
    float sum = 0.f;
#pragma unroll
    for (int i = 0; i < 16; ++i) sum += partial[(b * 128 + k8 * 16 + i) * NQ + q];
    red[pair][k8] = sum;
  }
  __syncthreads();
  if (tid < 84) {
    float sum = 0.f;
#pragma unroll
    for (int k = 0; k < 8; ++k) sum += red[tid][k];
    out[tid] = sum;     // tid == b*21 + q
  }
}

extern "C" void kernel_launch(void* const* d_in, const int* in_sizes, int n_in,
                              void* d_out, int out_size, void* d_ws, size_t ws_size,
                              hipStream_t stream) {
  const float* x = (const float*)d_in[0];   // (4,21) f32
  const float* w = (const float*)d_in[1];   // (3,21) f32
  float* out = (float*)d_out;               // (4,21) f32
  unsigned long long stp = (unsigned long long)d_ws;            // 16 MB fp16 state
  float* partial = (float*)((char*)d_ws + (((size_t)4 << 21) * 2));  // 512*21 f32
  if (ws_size < ((size_t)4 << 21) * 2 + 512 * NQ * 4) return;

  dim3 grid(256), blk(1024);
  k_L<true> <<<grid, blk, 0, stream>>>(x, w +  0, stp);
  k_H       <<<grid, blk, 0, stream>>>(w +  0, stp);
  k_L<false><<<grid, blk, 0, stream>>>(nullptr, w + 21, stp);
  k_H       <<<grid, blk, 0, stream>>>(w + 21, stp);
  k_L<false><<<grid, blk, 0, stream>>>(nullptr, w + 42, stp);
  k_Hfin    <<<grid, blk, 0, stream>>>(w + 42, stp, partial);
  k_red     <<<1, dim3(672), 0, stream>>>(partial, out);
}

// Round 14
// 97.023 us; speedup vs baseline: 1.3663x; 1.3663x over previous
//
#include <hip/hip_runtime.h>
#include <hip/hip_fp16.h>

// 21-qubit batched (B=4) state-vector simulator, 6 split passes + k_red.
// R14: R11 verbatim (fp16 LDS tiles 32KB, f32 compute, conflict-free slot
// algebra) with ONE change: __launch_bounds__(512,6) -> 3 blocks/CU,
// 6 waves/SIMD (VGPR cap 85, live set ~80 fits; R13 showed cap 64 spills).
// fp16 global state, XCD batch affinity. Qubit q <-> g-bit (20-q).

#define NQ 21
#define SHC(q) __shfl(cv, (q)), __shfl(sv, (q))

__device__ __forceinline__ int PH2B(int blk) {        // granule swizzle
  return blk ^ ((blk >> 3) & 7) ^ ((blk >> 6) & 7);
}

template<int Q>
__device__ __forceinline__ void ry32(float* v, float c, float s) {
#pragma unroll
  for (int k = 0; k < 16; ++k) {
    int l0 = ((k >> Q) << (Q + 1)) | (k & ((1 << Q) - 1));
    int l1 = l0 | (1 << Q);
    float a0 = v[l0], a1 = v[l1];
    v[l0] = c * a0 - s * a1;
    v[l1] = s * a0 + c * a1;
  }
}

template<int C, int T>
__device__ __forceinline__ void cnot32(float* v) {
  constexpr int lo = (C < T) ? C : T;
  constexpr int hi = (C < T) ? T : C;
#pragma unroll
  for (int k = 0; k < 8; ++k) {
    int i1 = ((k >> lo) << (lo + 1)) | (k & ((1 << lo) - 1));
    int i2 = ((i1 >> hi) << (hi + 1)) | (i1 & ((1 << hi) - 1));
    int a = i2 | (1 << C);
    int b = a | (1 << T);
    float tmp = v[a]; v[a] = v[b]; v[b] = tmp;
  }
}

// fp16 helpers: 4 amps (8B) <-> 4 f32 regs ; 2 amps <-> 1 uint
__device__ __forceinline__ void uh4(uint2 u, float* d) {
  __half2 h0 = *reinterpret_cast<__half2*>(&u.x);
  __half2 h1 = *reinterpret_cast<__half2*>(&u.y);
  float2 f0 = __half22float2(h0), f1 = __half22float2(h1);
  d[0] = f0.x; d[1] = f0.y; d[2] = f1.x; d[3] = f1.y;
}
__device__ __forceinline__ void ld4(const uint2* __restrict__ g, int idx, float* dst) {
  uh4(g[idx], dst);
}
__device__ __forceinline__ unsigned pkh(float a, float b) {
  __half2 h = __floats2half2_rn(a, b);
  return *reinterpret_cast<unsigned*>(&h);
}

#define A1 (tid | (rr << 9))
#define GH(l4) (((l4) & 0xF) | (t << 4) | (((l4) >> 4) << 11))

// sigma2-style write (S1/HS1): pairs over v-bit2 (b32 writes)
#define WR_SIGMA2(hs, v)                                                       \
  {                                                                            \
    const int pbs = (((tid >> 5) & 1) << 1) | ((tid & 31) << 2) |              \
                    (((tid >> 6) & 7) << 9);                                   \
    _Pragma("unroll") for (int i = 0; i < 16; ++i) {                           \
      int r = (i & 3) | ((i >> 2) << 3);                                       \
      int sl = pbs ^ (((i & 3) << 7) | ((i >> 2) << 12));                      \
      int a = (PH2B(sl >> 2) << 2) | (sl & 3);                                 \
      (hs)[a >> 1] = pkh((v)[r], (v)[r | 4]);                                  \
    }                                                                          \
  }

// sigma2-style read (S2/HS2): granule (4 amps) = uint2 b64 read + unpack
#define RD_SIGMA2(hs2, v)                                                      \
  {                                                                            \
    const int pbb = (tid & 31) | (((tid >> 5) & 3) << 5) |                     \
                    (((tid >> 7) & 3) << 10);                                  \
    _Pragma("unroll") for (int rr = 0; rr < 8; ++rr)                           \
      uh4((hs2)[PH2B(pbb ^ (rr << 7))], (v) + 4 * rr);                         \
  }

// ---------------- L pass: tile = bits 0..13, t = bits 14..20 ----------------
template<bool INIT>
__global__ __launch_bounds__(512, 6) void k_L(const float* __restrict__ x,
                                              const float* __restrict__ w,
                                              unsigned long long stp) {
  __shared__ __align__(16) unsigned hs[8192];         // 2^14 amps fp16 = 32 KB
  uint2* hs2 = reinterpret_cast<uint2*>(hs);
  const int tid = threadIdx.x, lane = tid & 63;
  const int bid = blockIdx.x;
  const int b = (bid & 7) >> 1;                       // XCD-pair affinity
  const int t = ((bid >> 3) << 1) | (bid & 1);
  float cv = 1.f, sv = 0.f;
  if (lane < NQ) sincosf(0.5f * w[lane], &sv, &cv);
  uint2* g2 = reinterpret_cast<uint2*>(stp) + ((size_t)b << 19) + ((size_t)t << 12);
  float v[32];

  // ---- S1: v = {amp0,amp1 | rr=amp11,12,13}: C(13,12),(12,11); RY q7,q8 ----
  if (INIT) {
    float cx = 1.f, sx = 0.f;
    if (lane < NQ) sincosf(0.5f * x[b * NQ + lane], &sx, &cx);
    float Qp = 1.f;
#pragma unroll
    for (int i = 0; i < 9; ++i) {            // tid bit i -> g(2+i) -> qubit 18-i
      float cq = __shfl(cx, 18 - i), sq = __shfl(sx, 18 - i);
      Qp *= ((tid >> i) & 1) ? sq : cq;
    }
    float hfac[2];
#pragma unroll
    for (int bb = 0; bb < 2; ++bb) {         // g13 = bb, h = g[13..20]
      int h = (t << 1) | bb;
      int h0 = h ^ (h >> 1);                 // pre-image of high chain
      float p = 1.f;
#pragma unroll
      for (int j = 0; j < 8; ++j) {
        float cq = __shfl(cx, 7 - j), sq = __shfl(sx, 7 - j);
        p *= ((h0 >> j) & 1) ? sq : cq;
      }
      hfac[bb] = p;
    }
    float c20 = __shfl(cx, 20), s20 = __shfl(sx, 20);
    float c19 = __shfl(cx, 19), s19 = __shfl(sx, 19);
    float c9  = __shfl(cx, 9),  s9  = __shfl(sx, 9);
    float c8  = __shfl(cx, 8),  s8  = __shfl(sx, 8);
    float w0t[4], w1t[4];
#pragma unroll
    for (int i = 0; i < 4; ++i) {
      w0t[i] = ((i & 1) ? s20 : c20) * ((i & 2) ? s19 : c19);  // amps 0,1
      w1t[i] = ((i & 1) ? s9  : c9 ) * ((i & 2) ? s8  : c8 );  // amps 11,12
    }
#pragma unroll
    for (int r = 0; r < 32; ++r)
      v[r] = hfac[(r >> 4) & 1] * w1t[(r >> 2) & 3] * w0t[r & 3] * Qp;
  } else {
#pragma unroll
    for (int rr = 0; rr < 8; ++rr) ld4(g2, A1, v + 4 * rr);
  }
  cnot32<4, 3>(v); cnot32<3, 2>(v);
  ry32<4>(v, SHC(7)); ry32<3>(v, SHC(8));
  WR_SIGMA2(hs, v);                          // s0=amp11
  __syncthreads();

  // ---- S2: v = {amp11,amp7 | rr=amp8,9,10}: C(11,10),(10,9),(9,8),(8,7) ----
  RD_SIGMA2(hs2, v);
  cnot32<0, 4>(v); cnot32<4, 3>(v); cnot32<3, 2>(v); cnot32<2, 1>(v);
  ry32<0>(v, SHC(9)); ry32<4>(v, SHC(10)); ry32<3>(v, SHC(11)); ry32<2>(v, SHC(12));
  __syncthreads();
  {
    // sigma3: s0=amp7(pair), s1=amp3, s2=amp4, s3=amp5, s4=amp6, s5=amp2,
    // s6=amp1, s7=amp0, s8..10=amp8..10, s11=amp11, s12,13=amp12,13
    const int pbs = (tid & 0x1E) | ((tid & 1) << 5) | (tid & 0x40) |
                    (((tid >> 5) & 1) << 7) | ((tid >> 7) << 12);
#pragma unroll
    for (int i = 0; i < 16; ++i) {
      int r = (i & 1) | ((i >> 1) << 2);
      int sl = pbs ^ ((((i >> 1) & 7) << 8) | ((i & 1) << 11));
      int a = (PH2B(sl >> 2) << 2) | (sl & 3);
      hs[a >> 1] = pkh(v[r], v[r | 2]);
    }
  }
  __syncthreads();

  // ---- S3: v = {amp7,amp3 | rr=amp4,5,6}: C(7,6),(6,5),(5,4),(4,3) ----
  {
    const int pbb = ((tid & 7) << 3) | (((tid >> 3) & 7) << 6) | (((tid >> 6) & 7) << 9);
#pragma unroll
    for (int rr = 0; rr < 8; ++rr) uh4(hs2[PH2B(pbb | rr)], v + 4 * rr);
  }
  cnot32<0, 4>(v); cnot32<4, 3>(v); cnot32<3, 2>(v); cnot32<2, 1>(v);
  ry32<0>(v, SHC(13)); ry32<4>(v, SHC(14)); ry32<3>(v, SHC(15)); ry32<2>(v, SHC(16));
  __syncthreads();
  {
    // identity'': s0=amp3, s1=amp4 (quads), s2=amp0, s3=amp1, s4=amp2,
    // s5=amp5, s6=amp6, s7=amp7, s8..13=amp8..13  (b64 quad writes)
    const int pbs = (((tid >> 2) & 1) << 2) | (((tid >> 1) & 1) << 3) |
                    ((tid & 1) << 4) | (((tid >> 3) & 7) << 8) |
                    (((tid >> 6) & 7) << 11);
#pragma unroll
    for (int i = 0; i < 8; ++i) {
      int r = (i & 1) | ((i >> 1) << 3);
      int sl = pbs ^ ((((i >> 1) & 1) << 5) | (((i >> 2) & 1) << 6) | ((i & 1) << 7));
      uint2 o; o.x = pkh(v[r], v[r | 2]); o.y = pkh(v[r | 4], v[r | 6]);
      hs2[PH2B(sl >> 2)] = o;
    }
  }
  __syncthreads();

  // ---- S4: v = {amp3,amp4 | rr=amp0,1,2}: C(3,2),(2,1),(1,0); RY q17..q19 ----
  {
    const int pbb = tid << 3;
#pragma unroll
    for (int rr = 0; rr < 8; ++rr) uh4(hs2[PH2B(pbb | rr)], v + 4 * rr);
  }
  cnot32<0, 4>(v); cnot32<4, 3>(v); cnot32<3, 2>(v);
  ry32<0>(v, SHC(17)); ry32<4>(v, SHC(18)); ry32<3>(v, SHC(19));
  {
    uint4* g4o = reinterpret_cast<uint4*>(g2);
#pragma unroll
    for (int i = 0; i < 4; ++i) {            // i = {a3, a4}
      int c = (i & 1) | ((i >> 1) << 1);
      uint4 o;
      o.x = pkh(v[c], v[c + 4]);   o.y = pkh(v[c + 8], v[c + 12]);
      o.z = pkh(v[c + 16], v[c + 20]); o.w = pkh(v[c + 24], v[c + 28]);
      g4o[(i & 1) | ((i >> 1) << 1) | (tid << 2)] = o;
    }
  }
}

// ---------------- H pass: tile = {g0..g5, g13..g20} (l0..l5, l6..l13) ----------------
__global__ __launch_bounds__(512, 6) void k_H(const float* __restrict__ w,
                                              unsigned long long stp) {
  __shared__ __align__(16) unsigned hs[8192];
  uint2* hs2 = reinterpret_cast<uint2*>(hs);
  const int tid = threadIdx.x, lane = tid & 63;
  const int bid = blockIdx.x;
  const int b = (bid & 7) >> 1;
  const int t = ((bid >> 3) << 1) | (bid & 1);
  float cv = 1.f, sv = 0.f;
  if (lane < NQ) sincosf(0.5f * w[lane], &sv, &cv);
  uint2* gb = reinterpret_cast<uint2*>(stp) + ((size_t)b << 19);
  float v[32];

  // ---- HS1: v = {l0,l1 | rr=l11,l12,l13}: wrap C(g0,g20); RY q20,q0,q1,q2;
  //      next-layer chain C(l13,l12),(l12,l11) ----
#pragma unroll
  for (int rr = 0; rr < 8; ++rr) ld4(gb, GH(A1), v + 4 * rr);
  cnot32<0, 4>(v);
  ry32<0>(v, SHC(20)); ry32<4>(v, SHC(0)); ry32<3>(v, SHC(1)); ry32<2>(v, SHC(2));
  cnot32<4, 3>(v); cnot32<3, 2>(v);
  WR_SIGMA2(hs, v);                          // s0=l11
  __syncthreads();

  // ---- HS2: v = {l11,l7 | rr=l8,l9,l10}: RY q3..q6; chain C(l11,l10)..(l8,l7) ----
  RD_SIGMA2(hs2, v);
  ry32<4>(v, SHC(3)); ry32<3>(v, SHC(4)); ry32<2>(v, SHC(5)); ry32<1>(v, SHC(6));
  cnot32<0, 4>(v); cnot32<4, 3>(v); cnot32<3, 2>(v); cnot32<2, 1>(v);
  __syncthreads();
  {
    // sigma3H: s0=l7(pair), s1=l5, s2=l0, s3=l1, s4=l6, s5=l2, s6=l3, s7=l4,
    // s8..10=l8..10, s11=l11, s12,13=l12,13
    const int pbs = (((tid >> 3) & 1) << 1) | (((tid >> 5) & 1) << 2) |
                    (((tid >> 6) & 1) << 3) | (tid & 16) | ((tid & 1) << 5) |
                    (((tid >> 1) & 1) << 6) | (((tid >> 2) & 1) << 7) |
                    ((tid >> 7) << 12);
#pragma unroll
    for (int i = 0; i < 16; ++i) {
      int r = (i & 1) | ((i >> 1) << 2);
      int sl = pbs ^ ((((i >> 1) & 7) << 8) | ((i & 1) << 11));
      int a = (PH2B(sl >> 2) << 2) | (sl & 3);
      hs[a >> 1] = pkh(v[r], v[r | 2]);
    }
  }
  __syncthreads();

  // ---- HS3: v = {l7,l5 | rr=l0,l1,l6}: chain C(l7,l6); store ----
  {
    const int pbb = ((tid & 7) << 3) | (((tid >> 3) & 7) << 6) | (((tid >> 6) & 7) << 9);
#pragma unroll
    for (int rr = 0; rr < 8; ++rr) uh4(hs2[PH2B(pbb | rr)], v + 4 * rr);
  }
  cnot32<0, 4>(v);
#pragma unroll
  for (int i = 0; i < 8; ++i) {              // i = {r0(l7), r1(l5), r4(l6)}
    int r0 = i & 1, r1 = (i >> 1) & 1, rh = (i >> 2) & 1;
    int c = r0 | (r1 << 1) | (rh << 4);
    int gidx = (tid & 7) | (r1 << 3) | (t << 4) |
               ((rh | (r0 << 1) | (((tid >> 3) & 0x3F) << 2)) << 11);
    uint2 o; o.x = pkh(v[c], v[c + 4]); o.y = pkh(v[c + 8], v[c + 12]);
    gb[gidx] = o;
  }
}

// ---------------- final H pass + measurement ----------------
__global__ __launch_bounds__(512, 6) void k_Hfin(const float* __restrict__ w,
                                                 unsigned long long stp,
                                                 float* __restrict__ partial) {
  __shared__ __align__(16) unsigned hs[8192];
  uint2* hs2 = reinterpret_cast<uint2*>(hs);
  float* red = reinterpret_cast<float*>(hs);          // reused post-sweeps
  const int tid = threadIdx.x, lane = tid & 63;
  const int bid = blockIdx.x;
  const int b = (bid & 7) >> 1;
  const int t = ((bid >> 3) << 1) | (bid & 1);
  float cv = 1.f, sv = 0.f;
  if (lane < NQ) sincosf(0.5f * w[lane], &sv, &cv);
  const uint2* gb = reinterpret_cast<const uint2*>(stp) + ((size_t)b << 19);
  float v[32];

  // ---- HS1f: wrap; RY q20,q0,q1,q2 ----
#pragma unroll
  for (int rr = 0; rr < 8; ++rr) ld4(gb, GH(A1), v + 4 * rr);
  cnot32<0, 4>(v);
  ry32<0>(v, SHC(20)); ry32<4>(v, SHC(0)); ry32<3>(v, SHC(1)); ry32<2>(v, SHC(2));
  WR_SIGMA2(hs, v);
  __syncthreads();

  // ---- HS2f: v = {l11,l7 | rr=l8,l9,l10}: RY q3..q6; measure ----
  RD_SIGMA2(hs2, v);
  __syncthreads();   // all LDS reads done; hs reused for reduction below
  ry32<4>(v, SHC(3)); ry32<3>(v, SHC(4)); ry32<2>(v, SHC(5)); ry32<1>(v, SHC(6));

  // v bits: 0=l11(q2), 1=l7(q6), 2=l8(q5), 3=l9(q4), 4=l10(q3)
  float S = 0, aq2 = 0, aq6 = 0, aq5 = 0, aq4 = 0, aq3 = 0;
#pragma unroll
  for (int r = 0; r < 32; ++r) {
    float p = v[r] * v[r];
    S += p;
    aq2 += (r & 1)  ? -p : p;
    aq6 += (r & 2)  ? -p : p;
    aq5 += (r & 4)  ? -p : p;
    aq4 += (r & 8)  ? -p : p;
    aq3 += (r & 16) ? -p : p;
  }
  float a21[21];
  a21[2] = aq2; a21[6] = aq6; a21[5] = aq5; a21[4] = aq4; a21[3] = aq3;
  a21[18] = (tid & 1)   ? -S : S;
  a21[17] = (tid & 2)   ? -S : S;
  a21[16] = (tid & 4)   ? -S : S;
  a21[15] = (tid & 8)   ? -S : S;
  a21[7]  = (tid & 16)  ? -S : S;
  a21[20] = (tid & 32)  ? -S : S;
  a21[19] = (tid & 64)  ? -S : S;
  a21[1]  = (tid & 128) ? -S : S;
  a21[0]  = (tid & 256) ? -S : S;
  a21[14] = (t & 1)  ? -S : S;     // t bits = g6..g12 -> q14..q8
  a21[13] = (t & 2)  ? -S : S;
  a21[12] = (t & 4)  ? -S : S;
  a21[11] = (t & 8)  ? -S : S;
  a21[10] = (t & 16) ? -S : S;
  a21[9]  = (t & 32) ? -S : S;
  a21[8]  = (t & 64) ? -S : S;

  const int wv = tid >> 6;
#pragma unroll
  for (int q = 0; q < 21; ++q) {
    float val = a21[q];
    val += __shfl_down(val, 32);
    val += __shfl_down(val, 16);
    val += __shfl_down(val, 8);
    val += __shfl_down(val, 4);
    val += __shfl_down(val, 2);
    val += __shfl_down(val, 1);
    if (lane == 0) red[q * 8 + wv] = val;
  }
  __syncthreads();
  if (tid < NQ) {
    float sum = 0.f;
#pragma unroll
    for (int k = 0; k < 8; ++k) sum += red[tid * 8 + k];
    partial[((b << 7) | t) * NQ + tid] = sum;
  }
}

// ---------------- deterministic final reduction (1 block x 672) ----------------
__global__ void k_red(const float* __restrict__ partial, float* __restrict__ out) {
  __shared__ float red[84][8];
  const int tid = threadIdx.x;
  const int pair = tid >> 3, k8 = tid & 7;
  if (pair < 84) {
    int b = pair / NQ, q = pair % NQ;
    float sum = 0.f;
#pragma unroll
    for (int i = 0; i < 16; ++i) sum += partial[(b * 128 + k8 * 16 + i) * NQ + q];
    red[pair][k8] = sum;
  }
  __syncthreads();
  if (tid < 84) {
    float sum = 0.f;
#pragma unroll
    for (int k = 0; k < 8; ++k) sum += red[tid][k];
    out[tid] = sum;     // tid == b*21 + q
  }
}

extern "C" void kernel_launch(void* const* d_in, const int* in_sizes, int n_in,
                              void* d_out, int out_size, void* d_ws, size_t ws_size,
                              hipStream_t stream) {
  const float* x = (const float*)d_in[0];   // (4,21) f32
  const float* w = (const float*)d_in[1];   // (3,21) f32
  float* out = (float*)d_out;               // (4,21) f32
  unsigned long long stp = (unsigned long long)d_ws;            // 16 MB fp16 state
  float* partial = (float*)((char*)d_ws + (((size_t)4 << 21) * 2));  // 512*21 f32
  if (ws_size < ((size_t)4 << 21) * 2 + 512 * NQ * 4) return;

  dim3 grid(512), blk(512);
  k_L<true> <<<grid, blk, 0, stream>>>(x, w +  0, stp);
  k_H       <<<grid, blk, 0, stream>>>(w +  0, stp);
  k_L<false><<<grid, blk, 0, stream>>>(nullptr, w + 21, stp);
  k_H       <<<grid, blk, 0, stream>>>(w + 21, stp);
  k_L<false><<<grid, blk, 0, stream>>>(nullptr, w + 42, stp);
  k_Hfin    <<<grid, blk, 0, stream>>>(w + 42, stp, partial);
  k_red     <<<1, dim3(672), 0, stream>>>(partial, out);
}

// Round 15
// 95.325 us; speedup vs baseline: 1.3907x; 1.0178x over previous
//
#include <hip/hip_runtime.h>
#include <hip/hip_fp16.h>

// 21-qubit batched (B=4) state-vector simulator, 6 split passes + reduce.
// FINAL (R8, best verified 95.2us): conflict-free LDS layouts — each
// inter-sweep layout's low slot bits come from (writer window ∩ reader window)
// so writes are paired b64 / quad b128 stores; reads are b128. Gate v-bit
// mappings derived per sweep. XCD batch affinity (batch = (bid&7)>>1 keeps
// each batch's 4MB fp16 state on one XCD pair's L2). fp16 global state,
// f32 LDS tiles. Qubit q <-> g-bit (20-q).
//
// Round history: 168.8 (R1 naive 7-pass) -> 121.4 (R2: 512-thr, 6-pass,
// closed-form init) -> 115.5 (R4: fp16 global state) -> 110.8 (R5: 4+3
// sweeps via sigma-relayouts) -> 95.2 (R8: conflict-free stores + XCD
// affinity). Falsified: prefetch via global_load_lds (R3), fused persistent
// kernel with device-scope barriers (R6/R7/R10 - agent-scope fences/polls
// cost more than kernel boundaries on 8-XCD), 8 waves/SIMD (R9/R13 - VGPR
// spills), fp16 LDS (R11 - cvt overhead = LDS savings), fewer barriers
// (R12 - neutral), 6 waves/SIMD (R14 - neutral; not latency-bound).

#define NQ 21
#define SHC(q) __shfl(cv, (q)), __shfl(sv, (q))

__device__ __forceinline__ int PH2B(int blk) {        // granule swizzle
  return blk ^ ((blk >> 3) & 7) ^ ((blk >> 6) & 7);
}

template<int Q>
__device__ __forceinline__ void ry32(float* v, float c, float s) {
#pragma unroll
  for (int k = 0; k < 16; ++k) {
    int l0 = ((k >> Q) << (Q + 1)) | (k & ((1 << Q) - 1));
    int l1 = l0 | (1 << Q);
    float a0 = v[l0], a1 = v[l1];
    v[l0] = c * a0 - s * a1;
    v[l1] = s * a0 + c * a1;
  }
}

template<int C, int T>
__device__ __forceinline__ void cnot32(float* v) {
  constexpr int lo = (C < T) ? C : T;
  constexpr int hi = (C < T) ? T : C;
#pragma unroll
  for (int k = 0; k < 8; ++k) {
    int i1 = ((k >> lo) << (lo + 1)) | (k & ((1 << lo) - 1));
    int i2 = ((i1 >> hi) << (hi + 1)) | (i1 & ((1 << hi) - 1));
    int a = i2 | (1 << C);
    int b = a | (1 << T);
    float tmp = v[a]; v[a] = v[b]; v[b] = tmp;
  }
}

__device__ __forceinline__ void ld4(const uint2* __restrict__ g, int idx, float* dst) {
  uint2 r = g[idx];
  __half2 h0 = *reinterpret_cast<__half2*>(&r.x);
  __half2 h1 = *reinterpret_cast<__half2*>(&r.y);
  float2 f0 = __half22float2(h0), f1 = __half22float2(h1);
  dst[0] = f0.x; dst[1] = f0.y; dst[2] = f1.x; dst[3] = f1.y;
}
__device__ __forceinline__ unsigned pkh(float a, float b) {
  __half2 h = __floats2half2_rn(a, b);
  return *reinterpret_cast<unsigned*>(&h);
}

#define A1 (tid | (rr << 9))
#define GH(l4) (((l4) & 0xF) | (t << 4) | (((l4) >> 4) << 11))

// sigma2-style write (S1/HS1): pairs over v-bit2; slot: s0=w2bit, s1=tid5,
// s2..6=tid0..4, s7,8=r0,r1, s9..11=tid6..8, s12,13=r3,r4.
#define WR_SIGMA2(s, v)                                                        \
  {                                                                            \
    const int pbs = (((tid >> 5) & 1) << 1) | ((tid & 31) << 2) |              \
                    (((tid >> 6) & 7) << 9);                                   \
    _Pragma("unroll") for (int i = 0; i < 16; ++i) {                           \
      int r = (i & 3) | ((i >> 2) << 3);                                       \
      int sl = pbs ^ (((i & 3) << 7) | ((i >> 2) << 12));                      \
      int a = (PH2B(sl >> 2) << 2) | (sl & 3);                                 \
      float2 o; o.x = (v)[r]; o.y = (v)[r | 4];                                \
      *reinterpret_cast<float2*>((s) + a) = o;                                 \
    }                                                                          \
  }

// sigma2-style read (S2/HS2): v0=w-bit at s0, v1=bit at s1, v2..4=rr (blk7..9)
#define RD_SIGMA2(s4, v4)                                                      \
  {                                                                            \
    const int pbb = (tid & 31) | (((tid >> 5) & 3) << 5) |                     \
                    (((tid >> 7) & 3) << 10);                                  \
    _Pragma("unroll") for (int rr = 0; rr < 8; ++rr)                          \
      (v4)[rr] = (s4)[PH2B(pbb ^ (rr << 7))];                                  \
  }

// ---------------- L pass: tile = bits 0..13, t = bits 14..20 ----------------
template<bool INIT>
__global__ __launch_bounds__(512, 4) void k_L(const float* __restrict__ x,
                                              const float* __restrict__ w,
                                              unsigned long long stp) {
  __shared__ __align__(16) float s[16384];
  float4* s4 = reinterpret_cast<float4*>(s);
  const int tid = threadIdx.x, lane = tid & 63;
  const int bid = blockIdx.x;
  const int b = (bid & 7) >> 1;                       // XCD-pair affinity
  const int t = ((bid >> 3) << 1) | (bid & 1);
  float cv = 1.f, sv = 0.f;
  if (lane < NQ) sincosf(0.5f * w[lane], &sv, &cv);
  uint2* g2 = reinterpret_cast<uint2*>(stp) + ((size_t)b << 19) + ((size_t)t << 12);
  float v[32];
  float4* v4 = reinterpret_cast<float4*>(v);

  // ---- S1: v = {amp0,amp1 | rr=amp11,12,13}: C(13,12),(12,11); RY q7,q8 ----
  if (INIT) {
    float cx = 1.f, sx = 0.f;
    if (lane < NQ) sincosf(0.5f * x[b * NQ + lane], &sx, &cx);
    float Qp = 1.f;
#pragma unroll
    for (int i = 0; i < 9; ++i) {            // tid bit i -> g(2+i) -> qubit 18-i
      float cq = __shfl(cx, 18 - i), sq = __shfl(sx, 18 - i);
      Qp *= ((tid >> i) & 1) ? sq : cq;
    }
    float hfac[2];
#pragma unroll
    for (int bb = 0; bb < 2; ++bb) {         // g13 = bb, h = g[13..20]
      int h = (t << 1) | bb;
      int h0 = h ^ (h >> 1);                 // pre-image of high chain
      float p = 1.f;
#pragma unroll
      for (int j = 0; j < 8; ++j) {
        float cq = __shfl(cx, 7 - j), sq = __shfl(sx, 7 - j);
        p *= ((h0 >> j) & 1) ? sq : cq;
      }
      hfac[bb] = p;
    }
    float c20 = __shfl(cx, 20), s20 = __shfl(sx, 20);
    float c19 = __shfl(cx, 19), s19 = __shfl(sx, 19);
    float c9  = __shfl(cx, 9),  s9  = __shfl(sx, 9);
    float c8  = __shfl(cx, 8),  s8  = __shfl(sx, 8);
    float w0t[4], w1t[4];
#pragma unroll
    for (int i = 0; i < 4; ++i) {
      w0t[i] = ((i & 1) ? s20 : c20) * ((i & 2) ? s19 : c19);  // amps 0,1
      w1t[i] = ((i & 1) ? s9  : c9 ) * ((i & 2) ? s8  : c8 );  // amps 11,12
    }
#pragma unroll
    for (int r = 0; r < 32; ++r)
      v[r] = hfac[(r >> 4) & 1] * w1t[(r >> 2) & 3] * w0t[r & 3] * Qp;
  } else {
#pragma unroll
    for (int rr = 0; rr < 8; ++rr) ld4(g2, A1, v + 4 * rr);
  }
  cnot32<4, 3>(v); cnot32<3, 2>(v);
  ry32<4>(v, SHC(7)); ry32<3>(v, SHC(8));
  WR_SIGMA2(s, v);                           // s0=amp11
  __syncthreads();

  // ---- S2: v = {amp11,amp7 | rr=amp8,9,10}: C(11,10),(10,9),(9,8),(8,7) ----
  RD_SIGMA2(s4, v4);
  cnot32<0, 4>(v); cnot32<4, 3>(v); cnot32<3, 2>(v); cnot32<2, 1>(v);
  ry32<0>(v, SHC(9)); ry32<4>(v, SHC(10)); ry32<3>(v, SHC(11)); ry32<2>(v, SHC(12));
  __syncthreads();
  {
    // sigma3: s0=amp7(pair), s1=amp3, s2=amp4, s3=amp5, s4=amp6, s5=amp2,
    // s6=amp1, s7=amp0, s8..10=amp8..10, s11=amp11, s12,13=amp12,13
    const int pbs = (tid & 0x1E) | ((tid & 1) << 5) | (tid & 0x40) |
                    (((tid >> 5) & 1) << 7) | ((tid >> 7) << 12);
#pragma unroll
    for (int i = 0; i < 16; ++i) {
      int r = (i & 1) | ((i >> 1) << 2);
      int sl = pbs ^ ((((i >> 1) & 7) << 8) | ((i & 1) << 11));
      int a = (PH2B(sl >> 2) << 2) | (sl & 3);
      float2 o; o.x = v[r]; o.y = v[r | 2];
      *reinterpret_cast<float2*>(s + a) = o;
    }
  }
  __syncthreads();

  // ---- S3: v = {amp7,amp3 | rr=amp4,5,6}: C(7,6),(6,5),(5,4),(4,3) ----
  {
    const int pbb = ((tid & 7) << 3) | (((tid >> 3) & 7) << 6) | (((tid >> 6) & 7) << 9);
#pragma unroll
    for (int rr = 0; rr < 8; ++rr) v4[rr] = s4[PH2B(pbb | rr)];
  }
  cnot32<0, 4>(v); cnot32<4, 3>(v); cnot32<3, 2>(v); cnot32<2, 1>(v);
  ry32<0>(v, SHC(13)); ry32<4>(v, SHC(14)); ry32<3>(v, SHC(15)); ry32<2>(v, SHC(16));
  __syncthreads();
  {
    // identity'': s0=amp3, s1=amp4 (quads), s2=amp0, s3=amp1, s4=amp2,
    // s5=amp5, s6=amp6, s7=amp7, s8..13=amp8..13
    const int pbs = (((tid >> 2) & 1) << 2) | (((tid >> 1) & 1) << 3) |
                    ((tid & 1) << 4) | (((tid >> 3) & 7) << 8) |
                    (((tid >> 6) & 7) << 11);
#pragma unroll
    for (int i = 0; i < 8; ++i) {
      int r = (i & 1) | ((i >> 1) << 3);
      int sl = pbs ^ ((((i >> 1) & 1) << 5) | (((i >> 2) & 1) << 6) | ((i & 1) << 7));
      int a = PH2B(sl >> 2) << 2;
      float4 o; o.x = v[r]; o.y = v[r | 2]; o.z = v[r | 4]; o.w = v[r | 6];
      *reinterpret_cast<float4*>(s + a) = o;
    }
  }
  __syncthreads();

  // ---- S4: v = {amp3,amp4 | rr=amp0,1,2}: C(3,2),(2,1),(1,0); RY q17..q19 ----
  {
    const int pbb = tid << 3;
#pragma unroll
    for (int rr = 0; rr < 8; ++rr) v4[rr] = s4[PH2B(pbb | rr)];
  }
  cnot32<0, 4>(v); cnot32<4, 3>(v); cnot32<3, 2>(v);
  ry32<0>(v, SHC(17)); ry32<4>(v, SHC(18)); ry32<3>(v, SHC(19));
  {
    uint4* g4o = reinterpret_cast<uint4*>(g2);
#pragma unroll
    for (int i = 0; i < 4; ++i) {            // i = {a3, a4}
      int c = (i & 1) | ((i >> 1) << 1);
      uint4 o;
      o.x = pkh(v[c], v[c + 4]);   o.y = pkh(v[c + 8], v[c + 12]);
      o.z = pkh(v[c + 16], v[c + 20]); o.w = pkh(v[c + 24], v[c + 28]);
      g4o[(i & 1) | ((i >> 1) << 1) | (tid << 2)] = o;
    }
  }
}

// ---------------- H pass: tile = {g0..g5, g13..g20} (l0..l5, l6..l13) ----------------
__global__ __launch_bounds__(512, 4) void k_H(const float* __restrict__ w,
                                              unsigned long long stp) {
  __shared__ __align__(16) float s[16384];
  float4* s4 = reinterpret_cast<float4*>(s);
  const int tid = threadIdx.x, lane = tid & 63;
  const int bid = blockIdx.x;
  const int b = (bid & 7) >> 1;
  const int t = ((bid >> 3) << 1) | (bid & 1);
  float cv = 1.f, sv = 0.f;
  if (lane < NQ) sincosf(0.5f * w[lane], &sv, &cv);
  uint2* gb = reinterpret_cast<uint2*>(stp) + ((size_t)b << 19);
  float v[32];
  float4* v4 = reinterpret_cast<float4*>(v);

  // ---- HS1: v = {l0,l1 | rr=l11,l12,l13}: wrap C(g0,g20); RY q20,q0,q1,q2;
  //      next-layer chain C(l13,l12),(l12,l11) ----
#pragma unroll
  for (int rr = 0; rr < 8; ++rr) ld4(gb, GH(A1), v + 4 * rr);
  cnot32<0, 4>(v);
  ry32<0>(v, SHC(20)); ry32<4>(v, SHC(0)); ry32<3>(v, SHC(1)); ry32<2>(v, SHC(2));
  cnot32<4, 3>(v); cnot32<3, 2>(v);
  WR_SIGMA2(s, v);                           // s0=l11
  __syncthreads();

  // ---- HS2: v = {l11,l7 | rr=l8,l9,l10}: RY q3..q6; chain C(l11,l10)..(l8,l7) ----
  RD_SIGMA2(s4, v4);
  ry32<4>(v, SHC(3)); ry32<3>(v, SHC(4)); ry32<2>(v, SHC(5)); ry32<1>(v, SHC(6));
  cnot32<0, 4>(v); cnot32<4, 3>(v); cnot32<3, 2>(v); cnot32<2, 1>(v);
  __syncthreads();
  {
    // sigma3H: s0=l7(pair), s1=l5, s2=l0, s3=l1, s4=l6, s5=l2, s6=l3, s7=l4,
    // s8..10=l8..10, s11=l11, s12,13=l12,13
    const int pbs = (((tid >> 3) & 1) << 1) | (((tid >> 5) & 1) << 2) |
                    (((tid >> 6) & 1) << 3) | (tid & 16) | ((tid & 1) << 5) |
                    (((tid >> 1) & 1) << 6) | (((tid >> 2) & 1) << 7) |
                    ((tid >> 7) << 12);
#pragma unroll
    for (int i = 0; i < 16; ++i) {
      int r = (i & 1) | ((i >> 1) << 2);
      int sl = pbs ^ ((((i >> 1) & 7) << 8) | ((i & 1) << 11));
      int a = (PH2B(sl >> 2) << 2) | (sl & 3);
      float2 o; o.x = v[r]; o.y = v[r | 2];
      *reinterpret_cast<float2*>(s + a) = o;
    }
  }
  __syncthreads();

  // ---- HS3: v = {l7,l5 | rr=l0,l1,l6}: chain C(l7,l6); store ----
  {
    const int pbb = ((tid & 7) << 3) | (((tid >> 3) & 7) << 6) | (((tid >> 6) & 7) << 9);
#pragma unroll
    for (int rr = 0; rr < 8; ++rr) v4[rr] = s4[PH2B(pbb | rr)];
  }
  cnot32<0, 4>(v);
#pragma unroll
  for (int i = 0; i < 8; ++i) {              // i = {r0(l7), r1(l5), r4(l6)}
    int r0 = i & 1, r1 = (i >> 1) & 1, rh = (i >> 2) & 1;
    int c = r0 | (r1 << 1) | (rh << 4);
    int gidx = (tid & 7) | (r1 << 3) | (t << 4) |
               ((rh | (r0 << 1) | (((tid >> 3) & 0x3F) << 2)) << 11);
    uint2 o; o.x = pkh(v[c], v[c + 4]); o.y = pkh(v[c + 8], v[c + 12]);
    gb[gidx] = o;
  }
}

// ---------------- final H pass + measurement ----------------
__global__ __launch_bounds__(512, 4) void k_Hfin(const float* __restrict__ w,
                                                 unsigned long long stp,
                                                 float* __restrict__ partial) {
  __shared__ __align__(16) float s[16384];
  float4* s4 = reinterpret_cast<float4*>(s);
  const int tid = threadIdx.x, lane = tid & 63;
  const int bid = blockIdx.x;
  const int b = (bid & 7) >> 1;
  const int t = ((bid >> 3) << 1) | (bid & 1);
  float cv = 1.f, sv = 0.f;
  if (lane < NQ) sincosf(0.5f * w[lane], &sv, &cv);
  const uint2* gb = reinterpret_cast<const uint2*>(stp) + ((size_t)b << 19);
  float v[32];
  float4* v4 = reinterpret_cast<float4*>(v);

  // ---- HS1f: wrap; RY q20,q0,q1,q2 ----
#pragma unroll
  for (int rr = 0; rr < 8; ++rr) ld4(gb, GH(A1), v + 4 * rr);
  cnot32<0, 4>(v);
  ry32<0>(v, SHC(20)); ry32<4>(v, SHC(0)); ry32<3>(v, SHC(1)); ry32<2>(v, SHC(2));
  WR_SIGMA2(s, v);
  __syncthreads();

  // ---- HS2f: v = {l11,l7 | rr=l8,l9,l10}: RY q3..q6; measure ----
  RD_SIGMA2(s4, v4);
  __syncthreads();   // all LDS reads done; s reused for reduction below
  ry32<4>(v, SHC(3)); ry32<3>(v, SHC(4)); ry32<2>(v, SHC(5)); ry32<1>(v, SHC(6));

  // v bits: 0=l11(q2), 1=l7(q6), 2=l8(q5), 3=l9(q4), 4=l10(q3)
  float S = 0, aq2 = 0, aq6 = 0, aq5 = 0, aq4 = 0, aq3 = 0;
#pragma unroll
  for (int r = 0; r < 32; ++r) {
    float p = v[r] * v[r];
    S += p;
    aq2 += (r & 1)  ? -p : p;
    aq6 += (r & 2)  ? -p : p;
    aq5 += (r & 4)  ? -p : p;
    aq4 += (r & 8)  ? -p : p;
    aq3 += (r & 16) ? -p : p;
  }
  float a21[21];
  a21[2] = aq2; a21[6] = aq6; a21[5] = aq5; a21[4] = aq4; a21[3] = aq3;
  a21[18] = (tid & 1)   ? -S : S;
  a21[17] = (tid & 2)   ? -S : S;
  a21[16] = (tid & 4)   ? -S : S;
  a21[15] = (tid & 8)   ? -S : S;
  a21[7]  = (tid & 16)  ? -S : S;
  a21[20] = (tid & 32)  ? -S : S;
  a21[19] = (tid & 64)  ? -S : S;
  a21[1]  = (tid & 128) ? -S : S;
  a21[0]  = (tid & 256) ? -S : S;
  a21[14] = (t & 1)  ? -S : S;     // t bits = g6..g12 -> q14..q8
  a21[13] = (t & 2)  ? -S : S;
  a21[12] = (t & 4)  ? -S : S;
  a21[11] = (t & 8)  ? -S : S;
  a21[10] = (t & 16) ? -S : S;
  a21[9]  = (t & 32) ? -S : S;
  a21[8]  = (t & 64) ? -S : S;

  const int wv = tid >> 6;
#pragma unroll
  for (int q = 0; q < 21; ++q) {
    float val = a21[q];
    val += __shfl_down(val, 32);
    val += __shfl_down(val, 16);
    val += __shfl_down(val, 8);
    val += __shfl_down(val, 4);
    val += __shfl_down(val, 2);
    val += __shfl_down(val, 1);
    if (lane == 0) s[q * 8 + wv] = val;
  }
  __syncthreads();
  if (tid < NQ) {
    float sum = 0.f;
#pragma unroll
    for (int k = 0; k < 8; ++k) sum += s[tid * 8 + k];
    partial[((b << 7) | t) * NQ + tid] = sum;
  }
}

// ---------------- deterministic final reduction (1 block x 672) ----------------
__global__ void k_red(const float* __restrict__ partial, float* __restrict__ out) {
  __shared__ float red[84][8];
  const int tid = threadIdx.x;
  const int pair = tid >> 3, k8 = tid & 7;
  if (pair < 84) {
    int b = pair / NQ, q = pair % NQ;
    float sum = 0.f;
#pragma unroll
    for (int i = 0; i < 16; ++i) sum += partial[(b * 128 + k8 * 16 + i) * NQ + q];
    red[pair][k8] = sum;
  }
  __syncthreads();
  if (tid < 84) {
    float sum = 0.f;
#pragma unroll
    for (int k = 0; k < 8; ++k) sum += red[tid][k];
    out[tid] = sum;     // tid == b*21 + q
  }
}

extern "C" void kernel_launch(void* const* d_in, const int* in_sizes, int n_in,
                              void* d_out, int out_size, void* d_ws, size_t ws_size,
                              hipStream_t stream) {
  const float* x = (const float*)d_in[0];   // (4,21) f32
  const float* w = (const float*)d_in[1];   // (3,21) f32
  float* out = (float*)d_out;               // (4,21) f32
  unsigned long long stp = (unsigned long long)d_ws;            // 16 MB fp16 state
  float* partial = (float*)((char*)d_ws + (((size_t)4 << 21) * 2));  // 512*21 f32
  if (ws_size < ((size_t)4 << 21) * 2 + 512 * NQ * 4) return;

  dim3 grid(512), blk(512);
  k_L<true> <<<grid, blk, 0, stream>>>(x, w +  0, stp);
  k_H       <<<grid, blk, 0, stream>>>(w +  0, stp);
  k_L<false><<<grid, blk, 0, stream>>>(nullptr, w + 21, stp);
  k_H       <<<grid, blk, 0, stream>>>(w + 21, stp);
  k_L<false><<<grid, blk, 0, stream>>>(nullptr, w + 42, stp);
  k_Hfin    <<<grid, blk, 0, stream>>>(w + 42, stp, partial);
  k_red     <<<1, dim3(672), 0, stream>>>(partial, out);
}